// Round 6
// baseline (148.195 us; speedup 1.0000x reference)
//
#include <hip/hip_runtime.h>

#define NN 768
#define UU 64
#define INF 136        // 2U+K
#define BB 2
#define SLOPE 0.01f

__device__ __forceinline__ float lrelu(float x) { return x > 0.f ? x : SLOPE * x; }

// ---- workspace layout (bytes) ----
// dinv : 0        (768*4 = 3072)
// s1   : 4096     (1536*4 = 6144)
// A    : 16384    (1536*136*4 = 835584)   hop-1  seq@W1[0:64]
// Bv   : 851968   (835584)                hop-1  seq@W1[64:128]
// P2   : 1687552  (835584)                hop-2  seq@W2[0:64]   (unscaled)
// Q2   : 2523136  (835584)                hop-2  seq@W2[64:128] (unscaled)
// -> end 3358720.  No zero-init required anywhere (all dense stores).

// ---------- precompute 4 rows of A/Bv from x @ W columns ----------
__device__ __forceinline__ void pre_rows(int r4, const float* __restrict__ x,
                                         const float* __restrict__ W,
                                         float* __restrict__ A, float* __restrict__ Bv,
                                         float (*xs)[UU], int tid) {
    { int rr = tid >> 6, u = tid & 63;
      xs[rr][u] = x[(size_t)(r4 + rr) * UU + u]; }
    __syncthreads();
    int m = tid;
    if (m < INF) {
        float a[4] = {0.f,0.f,0.f,0.f}, bv[4] = {0.f,0.f,0.f,0.f};
        for (int u = 0; u < UU; u++) {
            float wa = W[u * INF + m];
            float wb = W[(UU + u) * INF + m];
#pragma unroll
            for (int r = 0; r < 4; r++) { a[r] += xs[r][u] * wa; bv[r] += xs[r][u] * wb; }
        }
#pragma unroll
        for (int r = 0; r < 4; r++) {
            A [(size_t)(r4 + r) * INF + m] = a[r];
            Bv[(size_t)(r4 + r) * INF + m] = bv[r];
        }
    }
}

// blocks [0,768)     : row-degree scan -> dinv[i]   (reads all of rel, warms L3)
// blocks [768,1152)  : hop-1 A/Bv precompute (4 of 1536 (b,row) rows each)
// blocks [1152,1536) : hop-2 P2/Q2 precompute
__global__ void __launch_bounds__(256) k_setup(
        const float* __restrict__ rel, const float* __restrict__ seq,
        const float* __restrict__ W1, const float* __restrict__ W2,
        float* __restrict__ dinv,
        float* __restrict__ A, float* __restrict__ Bv,
        float* __restrict__ P2, float* __restrict__ Q2) {
    __shared__ float xs[4][UU];
    __shared__ int wcnt[4];
    int blk = blockIdx.x;
    int tid = threadIdx.x;

    if (blk >= NN) {
        int g = blk - NN;
        bool h2 = g >= 384;
        if (h2) g -= 384;
        pre_rows(g * 4, seq, h2 ? W2 : W1, h2 ? P2 : A, h2 ? Q2 : Bv, xs, tid);
        return;
    }

    int i = blk;
    int w = tid >> 6, lane = tid & 63;
    int j0 = w * 192;
    int cnt = 0;
#pragma unroll
    for (int it = 0; it < 3; it++) {
        int j = j0 + it * 64 + lane;
        const float4* rp = (const float4*)(rel + (size_t)(i * NN + j) * 8);
        float4 a = rp[0], b = rp[1];
        float s = a.x + a.y + a.z + a.w + b.x + b.y + b.z + b.w;
        cnt += __popcll(__ballot(s > 0.f));   // wave-uniform
    }
    if (lane == 0) wcnt[w] = cnt;
    __syncthreads();
    if (tid == 0) dinv[i] = 1.0f / (float)(wcnt[0] + wcnt[1] + wcnt[2] + wcnt[3]);
}

// Column-organized hop: one wave per output (b,j); iterate in-neighbors i.
// Wave scans rel column j (12 rounds, lane tests i=r*64+lane), broadcasts the
// active record's 8 rel values via wave-uniform __shfl (-> v_readlane/SGPR),
// accumulates s2 in a register. No atomics, no LDS, no zero-init.
// H1: store s1[b,j].   H2: store out[b,j,:] = seq[b,j,:] * s1_j * acc directly.
template<bool H2>
__global__ void __launch_bounds__(256) k_hop(
        const float* __restrict__ rel, const float* __restrict__ dinv,
        const float* __restrict__ Ar, const float* __restrict__ Br,
        const float* __restrict__ W, const float* __restrict__ b1,
        const float* __restrict__ w2, const float* __restrict__ b2,
        float* __restrict__ s1, const float* __restrict__ seq,
        float* __restrict__ out) {
    int lane = threadIdx.x & 63;
    int wid = (blockIdx.x * blockDim.x + threadIdx.x) >> 6;   // 0..1535
    int b = wid >= NN ? 1 : 0;
    int j = wid - b * NN;

    // 136-wide element ownership: e0 = 0..63, e1 = 64..127, e2 = 128..135 (lanes 0-7)
    int e0 = lane, e1 = 64 + lane, e2 = 128 + (lane & 7);

    const float* WR = W + 128 * INF;   // rel-input rows of the 136x136 weight
    float wr0[8], wr1[8], wr2[8];
#pragma unroll
    for (int k = 0; k < 8; k++) {
        const float* Wk = WR + k * INF;
        wr0[k] = Wk[e0]; wr1[k] = Wk[e1]; wr2[k] = Wk[e2];
    }
    float bb0 = b1[e0], bb1 = b1[e1], bb2 = b1[e2];
    float w20 = w2[e0], w21 = w2[e1], w22 = (lane < 8) ? w2[e2] : 0.f;
    float b2v = b2[0];

    // column-side (j) staged rows, hoisted for the whole wave
    const float* Bj = Br + ((size_t)b * NN + j) * INF;
    float bc0 = Bj[e0], bc1 = Bj[e1], bc2 = Bj[e2];
    float sjj = 1.f;
    if (H2) { sjj = s1[b * NN + j]; bc0 *= sjj; bc1 *= sjj; bc2 *= sjj; }

    float acc = 0.f;
    for (int r = 0; r < 12; r++) {
        int ib = r * 64 + lane;
        const float4* cp = (const float4*)(rel + ((size_t)ib * NN + j) * 8);
        float4 ca = cp[0], cb = cp[1];
        float sm = ca.x + ca.y + ca.z + ca.w + cb.x + cb.y + cb.z + cb.w;
        unsigned long long m = __ballot(sm > 0.f);
        while (m) {
            int s = __ffsll((unsigned long long)m) - 1;   // wave-uniform
            m &= m - 1;
            int i = r * 64 + s;
            float rv[8];
            rv[0] = __shfl(ca.x, s, 64); rv[1] = __shfl(ca.y, s, 64);
            rv[2] = __shfl(ca.z, s, 64); rv[3] = __shfl(ca.w, s, 64);
            rv[4] = __shfl(cb.x, s, 64); rv[5] = __shfl(cb.y, s, 64);
            rv[6] = __shfl(cb.z, s, 64); rv[7] = __shfl(cb.w, s, 64);
            float r0 = bb0, r1 = bb1, r2 = bb2;
#pragma unroll
            for (int k = 0; k < 8; k++) {
                r0 += rv[k] * wr0[k]; r1 += rv[k] * wr1[k]; r2 += rv[k] * wr2[k];
            }
            const float* Ai = Ar + ((size_t)b * NN + i) * INF;
            float a0 = Ai[e0], a1 = Ai[e1], a2 = Ai[e2];
            if (H2) { float si = s1[b * NN + i]; a0 *= si; a1 *= si; a2 *= si; }
            // lanes >= 8: w22 = 0 kills the duplicated e2 term (values finite)
            float dot = lrelu(r0 + a0 + bc0) * w20
                      + lrelu(r1 + a1 + bc1) * w21
                      + lrelu(r2 + a2 + bc2) * w22;
#pragma unroll
            for (int off = 32; off; off >>= 1) dot += __shfl_xor(dot, off, 64);
            acc += dinv[i] * lrelu(dot + b2v);
        }
    }

    if (H2) {
        float f = sjj * acc;                       // s1[b,j] * s2[b,j]
        size_t base = ((size_t)b * NN + j) * UU;
        out[base + lane] = seq[base + lane] * f;   // coalesced 256 B store
    } else {
        if (lane == 0) s1[b * NN + j] = acc;
    }
}

extern "C" void kernel_launch(void* const* d_in, const int* in_sizes, int n_in,
                              void* d_out, int out_size, void* d_ws, size_t ws_size,
                              hipStream_t stream) {
    const float* seq  = (const float*)d_in[0];   // (2,768,64)
    const float* rel  = (const float*)d_in[1];   // (768,768,8)
    const float* w1_1 = (const float*)d_in[2];   // (136,136)
    const float* b1_1 = (const float*)d_in[3];
    const float* w1_2 = (const float*)d_in[4];   // (136,1)
    const float* b1_2 = (const float*)d_in[5];
    const float* w2_1 = (const float*)d_in[6];
    const float* b2_1 = (const float*)d_in[7];
    const float* w2_2 = (const float*)d_in[8];
    const float* b2_2 = (const float*)d_in[9];
    float* out = (float*)d_out;

    char* ws = (char*)d_ws;
    float* dinv = (float*)(ws + 0);
    float* s1   = (float*)(ws + 4096);
    float* A    = (float*)(ws + 16384);
    float* Bv   = (float*)(ws + 851968);
    float* P2   = (float*)(ws + 1687552);
    float* Q2   = (float*)(ws + 2523136);

    // 1: row degrees + all four staged matmuls (warms rel into L3)
    k_setup<<<NN + 768, 256, 0, stream>>>(rel, seq, w1_1, w2_1, dinv, A, Bv, P2, Q2);
    // 2: hop 1, column-organized -> s1 (plain stores)
    k_hop<false><<<384, 256, 0, stream>>>(rel, dinv, A, Bv,
                                          w1_1, b1_1, w1_2, b1_2, s1, seq, out);
    // 3: hop 2, column-organized -> out directly (k_final folded, zero atomics)
    k_hop<true><<<384, 256, 0, stream>>>(rel, dinv, P2, Q2,
                                         w2_1, b2_1, w2_2, b2_2, s1, seq, out);
}

// Round 7
// 140.426 us; speedup vs baseline: 1.0553x; 1.0553x over previous
//
#include <hip/hip_runtime.h>

#define NN 768
#define UU 64
#define KK 8
#define INF 136        // 2U+K
#define BB 2
#define SLOPE 0.01f
#define CAP 80         // record slots per row/column (degree ~39.4 +- 6.0; clamped)
#define NSLOT (NN*CAP) // 61440
#define NP 4           // privatized accumulator copies (hop 1)
#define PSTRIDE 1552   // floats per copy (2*768 + 16 pad)

__device__ __forceinline__ float lrelu(float x) { return x > 0.f ? x : SLOPE * x; }

// ---- workspace layout (bytes) ----
// s1p      : 0        (NP*PSTRIDE*4 = 24832)
// colcnt   : 24832    (3072)   zeroed by setup; atomically bumped by hop1
// rowcnt   : 27904    (3072)
// dinv     : 30976    (3072)
// A        : 34048    (835584)   hop-1  seq@W1[0:64]
// Bv       : 869632   (835584)   hop-1  seq@W1[64:128]
// P2       : 1705216  (835584)   hop-2  seq@W2[0:64]   (unscaled)
// Q2       : 2540800  (835584)   hop-2  seq@W2[64:128] (unscaled)
// recs     : 3376384  (245760)   row-compacted records (j per (i,slot))
// relc     : 3622144  (1966080)  row-compacted rel values
// recs_col : 5588224  (245760)   column-compacted records (i per (j,slot))
// relc_col : 5833984  (1966080)  column-compacted rel values -> end 7800064

// ---------- precompute 4 rows of A/Bv from x @ W columns ----------
__device__ __forceinline__ void pre_rows(int r4, const float* __restrict__ x,
                                         const float* __restrict__ W,
                                         float* __restrict__ A, float* __restrict__ Bv,
                                         float (*xs)[UU], int tid) {
    { int rr = tid >> 6, u = tid & 63;
      xs[rr][u] = x[(size_t)(r4 + rr) * UU + u]; }
    __syncthreads();
    int m = tid;
    if (m < INF) {
        float a[4] = {0.f,0.f,0.f,0.f}, bv[4] = {0.f,0.f,0.f,0.f};
        for (int u = 0; u < UU; u++) {
            float wa = W[u * INF + m];
            float wb = W[(UU + u) * INF + m];
#pragma unroll
            for (int r = 0; r < 4; r++) { a[r] += xs[r][u] * wa; bv[r] += xs[r][u] * wb; }
        }
#pragma unroll
        for (int r = 0; r < 4; r++) {
            A [(size_t)(r4 + r) * INF + m] = a[r];
            Bv[(size_t)(r4 + r) * INF + m] = bv[r];
        }
    }
}

// blocks [0,768)      : row pair compaction + rel compaction + rowcnt/dinv
// blocks [768,1152)   : hop-1 A/Bv precompute (4 rows each) + zero s1p
// blocks [1152,1536)  : hop-2 P2/Q2 precompute (4 rows each) + zero colcnt
__global__ void __launch_bounds__(256) k_setup(
        const float* __restrict__ rel, const float* __restrict__ seq,
        const float* __restrict__ W1, const float* __restrict__ W2,
        int* __restrict__ recs, int* __restrict__ rowcnt, float* __restrict__ dinv,
        float* __restrict__ A, float* __restrict__ Bv,
        float* __restrict__ P2, float* __restrict__ Q2,
        float* __restrict__ s1p, int* __restrict__ colcnt,
        float* __restrict__ relc) {
    __shared__ float xs[4][UU];
    __shared__ int wcnt[4];
    int blk = blockIdx.x;
    int tid = threadIdx.x;

    if (blk >= NN) {  // precompute part
        int g = blk - NN;
        bool h2 = g >= 384;
        if (h2) g -= 384;
        int zi = g * 256 + tid;
        if (h2) { if (zi < NN) colcnt[zi] = 0; }
        else    { if (zi < NP * PSTRIDE) s1p[zi] = 0.f; }
        pre_rows(g * 4, seq, h2 ? W2 : W1, h2 ? P2 : A, h2 ? Q2 : Bv, xs, tid);
        return;
    }

    // ---- pair part: one block per row i ----
    int i = blk;
    int w = tid >> 6, lane = tid & 63;
    int j0 = w * 192;
    float4 ra4[3], rb4[3];
    float sums[3];
#pragma unroll
    for (int it = 0; it < 3; it++) {
        int j = j0 + it * 64 + lane;
        const float4* rp = (const float4*)(rel + (size_t)(i * NN + j) * KK);
        ra4[it] = rp[0]; rb4[it] = rp[1];
        sums[it] = ra4[it].x + ra4[it].y + ra4[it].z + ra4[it].w
                 + rb4[it].x + rb4[it].y + rb4[it].z + rb4[it].w;
    }
    int cnt = 0;
    int pos[3];
    bool act[3];
#pragma unroll
    for (int it = 0; it < 3; it++) {
        act[it] = sums[it] > 0.f;
        unsigned long long m = __ballot(act[it]);
        pos[it] = cnt + __popcll(m & ((1ull << lane) - 1));
        cnt += __popcll(m);
    }
    if (lane == 0) wcnt[w] = cnt;
    __syncthreads();
    int prefix = 0, total = 0;
#pragma unroll
    for (int ww = 0; ww < 4; ww++) {
        int c = wcnt[ww];
        total += c;
        if (ww < w) prefix += c;
    }
    if (tid == 0) {
        rowcnt[i] = total < CAP ? total : CAP;
        dinv[i] = 1.0f / (float)total;
    }
#pragma unroll
    for (int it = 0; it < 3; it++) {
        if (act[it]) {
            int rp = prefix + pos[it];
            if (rp < CAP) {
                recs[i * CAP + rp] = j0 + it * 64 + lane;
                float4* rc = (float4*)(relc + ((size_t)i * CAP + rp) * 8);
                rc[0] = ra4[it]; rc[1] = rb4[it];
            }
        }
    }
}

// hop 1 (row-organized, 8 records/wave, lanes 0-31 = b0, 32-63 = b1) -> s1p.
// Side job: scatter each record into column-compacted recs_col/relc_col
// (lane 0 only; colcnt zeroed by setup -> no race).
__global__ void __launch_bounds__(256) k_hop1(
        const int* __restrict__ recs, const int* __restrict__ rowcnt,
        const float* __restrict__ dinv, const float* __restrict__ relc,
        const float* __restrict__ Ar, const float* __restrict__ Br,
        const float* __restrict__ W1, const float* __restrict__ b1,
        const float* __restrict__ w2, const float* __restrict__ b2,
        float* __restrict__ sp, int* __restrict__ colcnt,
        int* __restrict__ recs_col, float* __restrict__ relc_col) {
    int lane = threadIdx.x & 63;
    int wid = (blockIdx.x * blockDim.x + threadIdx.x) >> 6;
    const int WPR = CAP / 8;                 // 10 waves per row
    int i = wid / WPR;
    int w0 = (wid - i * WPR) * 8;
    int cnt = rowcnt[i];
    if (w0 >= cnt) return;                   // dead wave: out before weight loads
    int nt = cnt - w0; if (nt > 8) nt = 8;

    int hl = lane & 31, b = lane >> 5;
    int e0 = hl, e1 = 32 + hl, e2 = 64 + hl, e3 = 96 + hl, e4 = 128 + (hl & 7);

    const float* W1R = W1 + 128 * INF;
    float wr0[8], wr1[8], wr2[8], wr3[8], wr4[8];
#pragma unroll
    for (int k = 0; k < 8; k++) {
        const float* Wk = W1R + k * INF;
        wr0[k] = Wk[e0]; wr1[k] = Wk[e1]; wr2[k] = Wk[e2]; wr3[k] = Wk[e3]; wr4[k] = Wk[e4];
    }
    float bb0 = b1[e0], bb1 = b1[e1], bb2 = b1[e2], bb3 = b1[e3], bb4 = b1[e4];
    float w20 = w2[e0], w21 = w2[e1], w22 = w2[e2], w23 = w2[e3];
    float w24 = (hl < 8) ? w2[e4] : 0.f;
    float b2v = b2[0];
    float di = dinv[i];

    const float* Ai = Ar + ((size_t)b * NN + i) * INF;
    float ai0 = Ai[e0], ai1 = Ai[e1], ai2 = Ai[e2], ai3 = Ai[e3], ai4 = Ai[e4];

    float* s = sp + (wid & (NP - 1)) * PSTRIDE + b * NN;

    int4 q0 = *(const int4*)(recs + i * CAP + w0);
    int4 q1 = *(const int4*)(recs + i * CAP + w0 + 4);
    int jj[8] = {q0.x, q0.y, q0.z, q0.w, q1.x, q1.y, q1.z, q1.w};
    const float4* rc = (const float4*)(relc + ((size_t)i * CAP + w0) * 8);

#pragma unroll
    for (int t = 0; t < 8; t++) {
        if (t >= nt) break;                  // wave-uniform
        int j = jj[t];
        float4 ra = rc[2 * t];
        float4 rb = rc[2 * t + 1];
        // column compaction side-channel (one lane; all lanes hold ra/rb)
        if (lane == 0) {
            int cp = atomicAdd(&colcnt[j], 1);
            if (cp < CAP) {
                recs_col[j * CAP + cp] = i;
                float4* dst = (float4*)(relc_col + ((size_t)j * CAP + cp) * 8);
                dst[0] = ra; dst[1] = rb;
            }
        }
        float rv[8] = {ra.x, ra.y, ra.z, ra.w, rb.x, rb.y, rb.z, rb.w};
        float r0 = bb0, r1 = bb1, r2 = bb2, r3 = bb3, r4 = bb4;
#pragma unroll
        for (int k = 0; k < 8; k++) {
            r0 += rv[k] * wr0[k]; r1 += rv[k] * wr1[k]; r2 += rv[k] * wr2[k];
            r3 += rv[k] * wr3[k]; r4 += rv[k] * wr4[k];
        }
        const float* Bj = Br + ((size_t)b * NN + j) * INF;
        float dot = lrelu(r0 + ai0 + Bj[e0]) * w20
                  + lrelu(r1 + ai1 + Bj[e1]) * w21
                  + lrelu(r2 + ai2 + Bj[e2]) * w22
                  + lrelu(r3 + ai3 + Bj[e3]) * w23
                  + lrelu(r4 + ai4 + Bj[e4]) * w24;
#pragma unroll
        for (int off = 16; off; off >>= 1) dot += __shfl_xor(dot, off, 64);
        if (hl == 0) atomicAdd(&s[j], lrelu(dot + b2v) * di);   // lane0->b0, lane32->b1
    }
}

// hop 2, column-organized + record-parallel: one block per column j.
// Warps 0,1 -> b=0; warps 2,3 -> b=1; warp takes every-2nd record of its column.
// Per record: 32B broadcast rel read, coalesced P2-row read, lane-parallel 136-dot
// (e0=lane, e1=64+lane, e2=128+(lane&7) masked), one 6-shfl reduce.
// Epilogue: LDS-combine the 2 warp partials per batch; write out row directly.
__global__ void __launch_bounds__(256) k_hop2c(
        const int* __restrict__ recs_col, const int* __restrict__ colcnt,
        const float* __restrict__ relc_col, const float* __restrict__ dinv,
        const float* __restrict__ s1p,
        const float* __restrict__ P2, const float* __restrict__ Q2,
        const float* __restrict__ W, const float* __restrict__ b1,
        const float* __restrict__ w2, const float* __restrict__ b2,
        const float* __restrict__ seq, float* __restrict__ out) {
    __shared__ float part[4];
    int j = blockIdx.x;
    int tid = threadIdx.x;
    int w = tid >> 6, lane = tid & 63;
    int b = w >> 1, half = w & 1;
    int e0 = lane, e1 = 64 + lane, e2 = 128 + (lane & 7);

    const float* WR = W + 128 * INF;
    float wr0[8], wr1[8], wr2[8];
#pragma unroll
    for (int k = 0; k < 8; k++) {
        const float* Wk = WR + k * INF;
        wr0[k] = Wk[e0]; wr1[k] = Wk[e1]; wr2[k] = Wk[e2];
    }
    float bb0 = b1[e0], bb1 = b1[e1], bb2 = b1[e2];
    float w20 = w2[e0], w21 = w2[e1], w22 = (lane < 8) ? w2[e2] : 0.f;
    float b2v = b2[0];

    float sjj = 0.f;
#pragma unroll
    for (int p = 0; p < NP; p++) sjj += s1p[p * PSTRIDE + b * NN + j];
    const float* Qj = Q2 + ((size_t)b * NN + j) * INF;
    float bc0 = Qj[e0] * sjj, bc1 = Qj[e1] * sjj, bc2 = Qj[e2] * sjj;

    int cnt = colcnt[j]; if (cnt > CAP) cnt = CAP;
    float acc = 0.f;
#pragma unroll 2
    for (int r = half; r < cnt; r += 2) {
        int i = recs_col[j * CAP + r];
        const float4* rp = (const float4*)(relc_col + ((size_t)j * CAP + r) * 8);
        float4 ra = rp[0], rb = rp[1];
        float rv[8] = {ra.x, ra.y, ra.z, ra.w, rb.x, rb.y, rb.z, rb.w};
        float r0 = bb0, r1 = bb1, r2 = bb2;
#pragma unroll
        for (int k = 0; k < 8; k++) {
            r0 += rv[k] * wr0[k]; r1 += rv[k] * wr1[k]; r2 += rv[k] * wr2[k];
        }
        float si = 0.f;
#pragma unroll
        for (int p = 0; p < NP; p++) si += s1p[p * PSTRIDE + b * NN + i];
        const float* Pi = P2 + ((size_t)b * NN + i) * INF;
        float a0 = Pi[e0] * si, a1 = Pi[e1] * si, a2 = Pi[e2] * si;
        float dot = lrelu(r0 + a0 + bc0) * w20
                  + lrelu(r1 + a1 + bc1) * w21
                  + lrelu(r2 + a2 + bc2) * w22;
#pragma unroll
        for (int off = 32; off; off >>= 1) dot += __shfl_xor(dot, off, 64);
        acc += dinv[i] * lrelu(dot + b2v);
    }
    if (lane == 0) part[w] = acc;
    __syncthreads();
    if (half == 0) {   // warps 0 and 2 write their batch's output row
        float s2 = part[2 * b] + part[2 * b + 1];
        float f = sjj * s2;
        size_t base = ((size_t)b * NN + j) * UU;
        out[base + lane] = seq[base + lane] * f;   // coalesced 256 B store
    }
}

extern "C" void kernel_launch(void* const* d_in, const int* in_sizes, int n_in,
                              void* d_out, int out_size, void* d_ws, size_t ws_size,
                              hipStream_t stream) {
    const float* seq  = (const float*)d_in[0];   // (2,768,64)
    const float* rel  = (const float*)d_in[1];   // (768,768,8)
    const float* w1_1 = (const float*)d_in[2];   // (136,136)
    const float* b1_1 = (const float*)d_in[3];
    const float* w1_2 = (const float*)d_in[4];   // (136,1)
    const float* b1_2 = (const float*)d_in[5];
    const float* w2_1 = (const float*)d_in[6];
    const float* b2_1 = (const float*)d_in[7];
    const float* w2_2 = (const float*)d_in[8];
    const float* b2_2 = (const float*)d_in[9];
    float* out = (float*)d_out;

    char* ws = (char*)d_ws;
    float* s1p     = (float*)(ws + 0);
    int*   colcnt  = (int*)  (ws + 24832);
    int*   rowcnt  = (int*)  (ws + 27904);
    float* dinv    = (float*)(ws + 30976);
    float* A       = (float*)(ws + 34048);
    float* Bv      = (float*)(ws + 869632);
    float* P2      = (float*)(ws + 1705216);
    float* Q2      = (float*)(ws + 2540800);
    int*   recs    = (int*)  (ws + 3376384);
    float* relc    = (float*)(ws + 3622144);
    int*   recs_col= (int*)  (ws + 5588224);
    float* relc_col= (float*)(ws + 5833984);

    // 1: row compaction + rowcnt/dinv + all four staged matmuls + s1p/colcnt zeroing
    k_setup<<<NN + 768, 256, 0, stream>>>(rel, seq, w1_1, w2_1, recs, rowcnt, dinv,
                                          A, Bv, P2, Q2, s1p, colcnt, relc);
    // 2: hop 1 (row-organized) -> s1p; also builds column-compacted records
    k_hop1<<<NSLOT / 32, 256, 0, stream>>>(recs, rowcnt, dinv, relc, A, Bv,
                                           w1_1, b1_1, w1_2, b1_2,
                                           s1p, colcnt, recs_col, relc_col);
    // 3: hop 2 (column-organized, record-parallel) -> out directly (k_final folded)
    k_hop2c<<<NN, 256, 0, stream>>>(recs_col, colcnt, relc_col, dinv, s1p,
                                    P2, Q2, w2_1, b2_1, w2_2, b2_2, seq, out);
}

// Round 8
// 129.191 us; speedup vs baseline: 1.1471x; 1.0870x over previous
//
#include <hip/hip_runtime.h>

#define NN 768
#define UU 64
#define KK 8
#define INF 136        // 2U+K
#define BB 2
#define SLOPE 0.01f
#define CAP 80         // record slots per row (degree ~39.4 +- 6.0; clamped)
#define NSLOT (NN*CAP) // 61440
#define NP 4           // privatized accumulator copies
#define PSTRIDE 1552   // floats per copy (2*768 + 16 pad)

__device__ __forceinline__ float lrelu(float x) { return x > 0.f ? x : SLOPE * x; }

// ---- workspace layout (bytes) ----
// s1p    : 0        (NP*PSTRIDE*4 = 24832)
// s2p    : 24832    (24832)
// rowcnt : 49664    (768*4)
// A      : 52736    (835584)   hop-1  seq@W1[0:64]
// Bv     : 888320   (835584)   hop-1  seq@W1[64:128]
// P2     : 1723904  (835584)   hop-2  seq@W2[0:64]   (unscaled)
// Q2     : 2559488  (835584)   hop-2  seq@W2[64:128] (unscaled)
// recs   : 3395072  (245760) -> end 3640832

// ---------- precompute 4 rows of A/Bv from x @ W columns ----------
__device__ __forceinline__ void pre_rows(int r4, const float* __restrict__ x,
                                         const float* __restrict__ W,
                                         float* __restrict__ A, float* __restrict__ Bv,
                                         float (*xs)[UU], int tid) {
    { int rr = tid >> 6, u = tid & 63;
      xs[rr][u] = x[(size_t)(r4 + rr) * UU + u]; }
    __syncthreads();
    int m = tid;
    if (m < INF) {
        float a[4] = {0.f,0.f,0.f,0.f}, bv[4] = {0.f,0.f,0.f,0.f};
        for (int u = 0; u < UU; u++) {
            float wa = W[u * INF + m];
            float wb = W[(UU + u) * INF + m];
#pragma unroll
            for (int r = 0; r < 4; r++) { a[r] += xs[r][u] * wa; bv[r] += xs[r][u] * wb; }
        }
#pragma unroll
        for (int r = 0; r < 4; r++) {
            A [(size_t)(r4 + r) * INF + m] = a[r];
            Bv[(size_t)(r4 + r) * INF + m] = bv[r];
        }
    }
}

// blocks [0,768)      : pair compaction into fixed per-row segments (no global atomic)
// blocks [768,1152)   : hop-1 A/Bv precompute (4 rows each) + zero s1p
// blocks [1152,1536)  : hop-2 P2/Q2 precompute (4 rows each) + zero s2p
__global__ void __launch_bounds__(256) k_setup(
        const float* __restrict__ rel, const float* __restrict__ seq,
        const float* __restrict__ W1, const float* __restrict__ W2,
        int* __restrict__ recs, int* __restrict__ rowcnt,
        float* __restrict__ A, float* __restrict__ Bv,
        float* __restrict__ P2, float* __restrict__ Q2,
        float* __restrict__ s1p, float* __restrict__ s2p) {
    __shared__ float xs[4][UU];
    __shared__ int wcnt[4];
    int blk = blockIdx.x;
    int tid = threadIdx.x;

    if (blk >= NN) {  // precompute part
        int g = blk - NN;
        bool h2 = g >= 384;
        if (h2) g -= 384;
        float* z = h2 ? s2p : s1p;
        int zi = g * 256 + tid;
        if (zi < NP * PSTRIDE) z[zi] = 0.f;   // accumulator zeroing (was hipMemsetAsync)
        pre_rows(g * 4, seq, h2 ? W2 : W1, h2 ? P2 : A, h2 ? Q2 : Bv, xs, tid);
        return;
    }

    // ---- pair part: one block per row i, records land at recs[i*CAP ...] ----
    int i = blk;
    int w = tid >> 6, lane = tid & 63;
    int j0 = w * 192;
    float sums[3];
#pragma unroll
    for (int it = 0; it < 3; it++) {
        int j = j0 + it * 64 + lane;
        const float4* rp = (const float4*)(rel + (size_t)(i * NN + j) * KK);
        float4 a = rp[0], b = rp[1];
        sums[it] = a.x + a.y + a.z + a.w + b.x + b.y + b.z + b.w;
    }
    int cnt = 0;
    int pos[3];
    bool act[3];
#pragma unroll
    for (int it = 0; it < 3; it++) {
        act[it] = sums[it] > 0.f;
        unsigned long long m = __ballot(act[it]);
        pos[it] = cnt + __popcll(m & ((1ull << lane) - 1));
        cnt += __popcll(m);
    }
    if (lane == 0) wcnt[w] = cnt;
    __syncthreads();
    int prefix = 0, total = 0;
#pragma unroll
    for (int ww = 0; ww < 4; ww++) {
        int c = wcnt[ww];
        total += c;
        if (ww < w) prefix += c;
    }
    if (tid == 0) rowcnt[i] = total < CAP ? total : CAP;
#pragma unroll
    for (int it = 0; it < 3; it++) {
        if (act[it]) {
            int rp = prefix + pos[it];
            if (rp < CAP) recs[i * CAP + rp] = j0 + it * 64 + lane;
        }
    }
}

// one wave per 4 slots of one row; lanes 0-31 = batch 0, lanes 32-63 = batch 1.
// Row-side values (A row, s1_i, 1/D[i]) hoisted out of the record loop.
// H2: staged rows are unscaled P2/Q2; apply s1_i / s1_j scalars here.
template<bool H2>
__global__ void __launch_bounds__(256) k_hop(
        const int* __restrict__ recs, const int* __restrict__ rowcnt,
        const float* __restrict__ Ar, const float* __restrict__ Br,
        const float* __restrict__ rel, const float* __restrict__ W1,
        const float* __restrict__ b1, const float* __restrict__ w2,
        const float* __restrict__ b2, const float* __restrict__ sc,
        float* __restrict__ sp) {
    int lane = threadIdx.x & 63;
    int wid = (blockIdx.x * blockDim.x + threadIdx.x) >> 6;
    int i = wid / (CAP / 4);                 // 20 waves per row
    int w0 = (wid - i * (CAP / 4)) * 4;      // slot offset within row
    int cnt = rowcnt[i];
    if (w0 >= cnt) return;                   // dead wave: out before weight loads

    int hl = lane & 31, b = lane >> 5;
    int e0 = hl, e1 = 32 + hl, e2 = 64 + hl, e3 = 96 + hl, e4 = 128 + (hl & 7);

    const float* W1R = W1 + 128 * INF;
    float wr0[8], wr1[8], wr2[8], wr3[8], wr4[8];
#pragma unroll
    for (int k = 0; k < 8; k++) {
        const float* Wk = W1R + k * INF;
        wr0[k] = Wk[e0]; wr1[k] = Wk[e1]; wr2[k] = Wk[e2]; wr3[k] = Wk[e3]; wr4[k] = Wk[e4];
    }
    float bb0 = b1[e0], bb1 = b1[e1], bb2 = b1[e2], bb3 = b1[e3], bb4 = b1[e4];
    float w20 = w2[e0], w21 = w2[e1], w22 = w2[e2], w23 = w2[e3];
    float w24 = (hl < 8) ? w2[e4] : 0.f;
    float b2v = b2[0];
    float di = 1.0f / (float)cnt;

    const float* Ai = Ar + ((size_t)b * NN + i) * INF;
    float ai0 = Ai[e0], ai1 = Ai[e1], ai2 = Ai[e2], ai3 = Ai[e3], ai4 = Ai[e4];
    if (H2) {
        float si = 0.f;
#pragma unroll
        for (int p = 0; p < NP; p++) si += sc[p * PSTRIDE + b * NN + i];
        ai0 *= si; ai1 *= si; ai2 *= si; ai3 *= si; ai4 *= si;
    }

    float* s = sp + (wid & (NP - 1)) * PSTRIDE + b * NN;

    int4 q = *(const int4*)(recs + i * CAP + w0);
    int jj[4] = {q.x, q.y, q.z, q.w};
    int nt = cnt - w0;

#pragma unroll
    for (int t = 0; t < 4; t++) {
        if (t >= nt) break;                  // wave-uniform
        int j = jj[t];
        const float* relp = rel + ((size_t)i * NN + j) * KK;
        float4 ra = ((const float4*)relp)[0];
        float4 rb = ((const float4*)relp)[1];
        float rv[8] = {ra.x, ra.y, ra.z, ra.w, rb.x, rb.y, rb.z, rb.w};
        float r0 = bb0, r1 = bb1, r2 = bb2, r3 = bb3, r4 = bb4;
#pragma unroll
        for (int k = 0; k < 8; k++) {
            r0 += rv[k] * wr0[k]; r1 += rv[k] * wr1[k]; r2 += rv[k] * wr2[k];
            r3 += rv[k] * wr3[k]; r4 += rv[k] * wr4[k];
        }
        const float* Bj = Br + ((size_t)b * NN + j) * INF;
        float sj = 1.f;
        if (H2) {
            sj = 0.f;
#pragma unroll
            for (int p = 0; p < NP; p++) sj += sc[p * PSTRIDE + b * NN + j];
        }
        float dot = lrelu(r0 + ai0 + sj * Bj[e0]) * w20
                  + lrelu(r1 + ai1 + sj * Bj[e1]) * w21
                  + lrelu(r2 + ai2 + sj * Bj[e2]) * w22
                  + lrelu(r3 + ai3 + sj * Bj[e3]) * w23
                  + lrelu(r4 + ai4 + sj * Bj[e4]) * w24;
#pragma unroll
        for (int off = 16; off; off >>= 1) dot += __shfl_xor(dot, off, 64);
        if (hl == 0) atomicAdd(&s[j], lrelu(dot + b2v) * di);   // lane 0 -> b0, lane 32 -> b1
    }
}

// out[b,j,u] = seq[b,j,u] * sum(s1 copies)[b,j] * sum(s2 copies)[b,j]
__global__ void __launch_bounds__(256) k_final(const float4* __restrict__ seq,
                                               const float* __restrict__ s1p,
                                               const float* __restrict__ s2p,
                                               float4* __restrict__ out) {
    int idx = blockIdx.x * blockDim.x + threadIdx.x;   // 24576 float4's
    int bj = idx >> 4;                                 // 16 float4 per (b,j) row
    float f1 = 0.f, f2 = 0.f;
#pragma unroll
    for (int p = 0; p < NP; p++) { f1 += s1p[p * PSTRIDE + bj]; f2 += s2p[p * PSTRIDE + bj]; }
    float f = f1 * f2;
    float4 v = seq[idx];
    v.x *= f; v.y *= f; v.z *= f; v.w *= f;
    out[idx] = v;
}

extern "C" void kernel_launch(void* const* d_in, const int* in_sizes, int n_in,
                              void* d_out, int out_size, void* d_ws, size_t ws_size,
                              hipStream_t stream) {
    const float* seq  = (const float*)d_in[0];   // (2,768,64)
    const float* rel  = (const float*)d_in[1];   // (768,768,8)
    const float* w1_1 = (const float*)d_in[2];   // (136,136)
    const float* b1_1 = (const float*)d_in[3];
    const float* w1_2 = (const float*)d_in[4];   // (136,1)
    const float* b1_2 = (const float*)d_in[5];
    const float* w2_1 = (const float*)d_in[6];
    const float* b2_1 = (const float*)d_in[7];
    const float* w2_2 = (const float*)d_in[8];
    const float* b2_2 = (const float*)d_in[9];
    float* out = (float*)d_out;

    char* ws = (char*)d_ws;
    float* s1p   = (float*)(ws + 0);
    float* s2p   = (float*)(ws + 24832);
    int* rowcnt  = (int*)  (ws + 49664);
    float* A     = (float*)(ws + 52736);
    float* Bv    = (float*)(ws + 888320);
    float* P2    = (float*)(ws + 1723904);
    float* Q2    = (float*)(ws + 2559488);
    int* recs    = (int*)  (ws + 3395072);

    // 1: pairs + hop-1 A/Bv + hop-2 P2/Q2 + accumulator zeroing (memset node eliminated)
    k_setup<<<NN + 768, 256, 0, stream>>>(rel, seq, w1_1, w2_1, recs, rowcnt,
                                          A, Bv, P2, Q2, s1p, s2p);
    // 2: hop 1
    k_hop<false><<<NSLOT / 16, 256, 0, stream>>>(recs, rowcnt, A, Bv, rel,
                                                 w1_1, b1_1, w1_2, b1_2, nullptr, s1p);
    // 3: hop 2 (s1 scaling folded in; k_pre eliminated)
    k_hop<true><<<NSLOT / 16, 256, 0, stream>>>(recs, rowcnt, P2, Q2, rel,
                                                w2_1, b2_1, w2_2, b2_2, s1p, s2p);
    // 4: final elementwise
    k_final<<<BB * NN * UU / 4 / 256, 256, 0, stream>>>((const float4*)seq, s1p, s2p,
                                                        (float4*)out);
}